// Round 2
// baseline (543.209 us; speedup 1.0000x reference)
//
#include <hip/hip_runtime.h>
#include <hip/hip_bf16.h>

typedef __fp16 f16x2 __attribute__((ext_vector_type(2)));
typedef __fp16 f16x8 __attribute__((ext_vector_type(8)));
typedef float  f32x4 __attribute__((ext_vector_type(4)));

#define NN   8192
#define INC  256
#define OUTC 256
#define RR   8
#define BB   4
#define K2   2048   // INC * RR

// ---------------------------------------------------------------------------
// Kernel 1: W2T[o][k] = sum_b w_rel[r,b] * w_bases[b,i,o],  k = i*8 + r
// Output fp32 [256][2048] (o-major so it is the A operand of G2).
// ---------------------------------------------------------------------------
__global__ void build_w2t(const float* __restrict__ wb, const float* __restrict__ wr,
                          float* __restrict__ W2T) {
    int k = blockIdx.x;          // 0..2047
    int o = threadIdx.x;         // 0..255
    int i = k >> 3, r = k & 7;
    float s = 0.f;
#pragma unroll
    for (int b = 0; b < BB; ++b)
        s = fmaf(wr[r * BB + b], wb[((b << 8) + i) * OUTC + o], s);
    W2T[o * K2 + k] = s;
}

// ---------------------------------------------------------------------------
// Unified split-K MFMA GEMM: C[M][N] += A[M][K] * Bt[N][K]^T
// A, Bt fp32 in global; converted to f16 at LDS staging; C fp32 via atomicAdd.
// Tile: BM=128, BN=128, BK=32; 256 threads = 4 waves; wave = 64x64 = 4x4 MFMA.
// mfma_f32_16x16x32_f16 layouts (verified on gfx950):
//   A/B frag: lane holds [row|col = lane&15][k = (lane>>4)*8 + j], j=0..7
//   C/D:      col = lane&15, row = (lane>>4)*4 + reg
// ---------------------------------------------------------------------------
constexpr int BM = 128, BN = 128, BK = 32;

__global__ __launch_bounds__(256, 2)
void gemm_f16_splitk(const float* __restrict__ A, const float* __restrict__ Bt,
                     float* __restrict__ C, int M, int N, int K, int kPerSplit) {
    __shared__ __align__(16) __fp16 As[BM][BK];
    __shared__ __align__(16) __fp16 Bs[BN][BK];

    const int bm = blockIdx.x * BM;
    const int bn = blockIdx.y * BN;
    const int k0 = blockIdx.z * kPerSplit;
    const int kEnd = k0 + kPerSplit;

    const int tid  = threadIdx.x;
    const int lane = tid & 63;
    const int wave = tid >> 6;          // 0..3
    const int wm   = (wave >> 1) * 64;  // 0 or 64
    const int wn   = (wave & 1) * 64;   // 0 or 64
    const int quad = lane >> 4;         // 0..3
    const int l16  = lane & 15;

    f32x4 acc[4][4];
#pragma unroll
    for (int ti = 0; ti < 4; ++ti)
#pragma unroll
        for (int tj = 0; tj < 4; ++tj)
            acc[ti][tj] = (f32x4){0.f, 0.f, 0.f, 0.f};

    for (int kc = k0; kc < kEnd; kc += BK) {
        // ---- stage A tile: 128 rows x 32 k = 1024 float4, 4 per thread ----
#pragma unroll
        for (int s = 0; s < 4; ++s) {
            int c   = tid + s * 256;
            int row = c >> 3;          // 0..127
            int kq  = c & 7;           // 0..7 (float4 index within the 32-k row)
            const float4 v = *reinterpret_cast<const float4*>(
                &A[(size_t)(bm + row) * K + kc + kq * 4]);
            f16x2 p0 = __builtin_amdgcn_cvt_pkrtz(v.x, v.y);
            f16x2 p1 = __builtin_amdgcn_cvt_pkrtz(v.z, v.w);
            *reinterpret_cast<f16x2*>(&As[row][kq * 4 + 0]) = p0;
            *reinterpret_cast<f16x2*>(&As[row][kq * 4 + 2]) = p1;
        }
        // ---- stage B tile: 128 n-rows x 32 k ----
#pragma unroll
        for (int s = 0; s < 4; ++s) {
            int c   = tid + s * 256;
            int row = c >> 3;
            int kq  = c & 7;
            const float4 v = *reinterpret_cast<const float4*>(
                &Bt[(size_t)(bn + row) * K + kc + kq * 4]);
            f16x2 p0 = __builtin_amdgcn_cvt_pkrtz(v.x, v.y);
            f16x2 p1 = __builtin_amdgcn_cvt_pkrtz(v.z, v.w);
            *reinterpret_cast<f16x2*>(&Bs[row][kq * 4 + 0]) = p0;
            *reinterpret_cast<f16x2*>(&Bs[row][kq * 4 + 2]) = p1;
        }
        __syncthreads();

        // ---- fragments + 16 MFMA ----
        f16x8 af[4], bf[4];
#pragma unroll
        for (int t = 0; t < 4; ++t) {
            af[t] = *reinterpret_cast<const f16x8*>(&As[wm + t * 16 + l16][quad * 8]);
            bf[t] = *reinterpret_cast<const f16x8*>(&Bs[wn + t * 16 + l16][quad * 8]);
        }
#pragma unroll
        for (int ti = 0; ti < 4; ++ti)
#pragma unroll
            for (int tj = 0; tj < 4; ++tj)
                acc[ti][tj] = __builtin_amdgcn_mfma_f32_16x16x32_f16(
                    af[ti], bf[tj], acc[ti][tj], 0, 0, 0);
        __syncthreads();
    }

    // ---- epilogue: atomic accumulate (split-K) ----
#pragma unroll
    for (int ti = 0; ti < 4; ++ti) {
#pragma unroll
        for (int tj = 0; tj < 4; ++tj) {
#pragma unroll
            for (int r = 0; r < 4; ++r) {
                int row = bm + wm + ti * 16 + quad * 4 + r;
                int col = bn + wn + tj * 16 + l16;
                atomicAdd(&C[(size_t)row * N + col], acc[ti][tj][r]);
            }
        }
    }
}

// ---------------------------------------------------------------------------
extern "C" void kernel_launch(void* const* d_in, const int* in_sizes, int n_in,
                              void* d_out, int out_size, void* d_ws, size_t ws_size,
                              hipStream_t stream) {
    const float* a  = (const float*)d_in[0];   // [8192][8192]
    const float* x  = (const float*)d_in[1];   // [8192][256][8] -> [m][k=i*8+r]
    const float* wb = (const float*)d_in[2];   // [4][256][256]
    const float* wr = (const float*)d_in[3];   // [8][4]
    float* out = (float*)d_out;                // [8192][256]

    float* W2T = (float*)d_ws;                                     // [256][2048], 2 MB
    float* yT  = (float*)((char*)d_ws + (size_t)OUTC * K2 * 4);    // [256][8192], 8 MB

    // zero atomic-accumulation targets (harness poisons them with 0xAA)
    (void)hipMemsetAsync(yT,  0, (size_t)OUTC * NN * sizeof(float), stream);
    (void)hipMemsetAsync(out, 0, (size_t)NN * OUTC * sizeof(float), stream);

    // 1) combined basis weights, transposed: W2T[o][k]
    build_w2t<<<dim3(K2), dim3(256), 0, stream>>>(wb, wr, W2T);

    // 2) yT[o][m] = sum_k W2T[o][k] * x[m][k]   (M=256, N=8192, K=2048, split 2)
    gemm_f16_splitk<<<dim3(2, 64, 2), dim3(256), 0, stream>>>(
        W2T, x, yT, 256, NN, K2, 1024);

    // 3) out[n][o] = sum_m a[n][m] * yT[o][m]   (M=8192, N=256, K=8192, split 2)
    gemm_f16_splitk<<<dim3(64, 2, 2), dim3(256), 0, stream>>>(
        a, yT, out, NN, OUTC, NN, 4096);
}

// Round 3
// 521.003 us; speedup vs baseline: 1.0426x; 1.0426x over previous
//
#include <hip/hip_runtime.h>
#include <hip/hip_bf16.h>

typedef __fp16 f16x2 __attribute__((ext_vector_type(2)));
typedef __fp16 f16x8 __attribute__((ext_vector_type(8)));
typedef float  f32x4 __attribute__((ext_vector_type(4)));

#define NN   8192
#define INC  256
#define OUTC 256
#define RR   8
#define BB   4
#define K2   2048   // INC * RR

// ---------------------------------------------------------------------------
// Kernel 1: W2T[o][k] = sum_b w_rel[r,b] * w_bases[b,i,o],  k = i*8 + r
// ---------------------------------------------------------------------------
__global__ void build_w2t(const float* __restrict__ wb, const float* __restrict__ wr,
                          float* __restrict__ W2T) {
    int k = blockIdx.x;          // 0..2047
    int o = threadIdx.x;         // 0..255
    int i = k >> 3, r = k & 7;
    float s = 0.f;
#pragma unroll
    for (int b = 0; b < BB; ++b)
        s = fmaf(wr[r * BB + b], wb[((b << 8) + i) * OUTC + o], s);
    W2T[o * K2 + k] = s;
}

// ---------------------------------------------------------------------------
// Unified split-K MFMA GEMM: C[M][N] += A[M][K] * Bt[N][K]^T
// fp32 inputs converted to f16 at LDS staging; fp32 atomicAdd epilogue.
// Tile: BM=128, BN=128, BK=32; 256 threads = 4 waves; wave = 64x64 = 4x4 MFMA.
// LDS rows padded to 40 f16 (80 B) so frag reads hit bank (l16*20+quad*4)%32
// -> max 2-way aliasing (free), vs 8-way at stride 64 B.
// ---------------------------------------------------------------------------
constexpr int BM = 128, BN = 128, BK = 32, BKP = 40;

__global__ __launch_bounds__(256, 2)
void gemm_f16_splitk(const float* __restrict__ A, const float* __restrict__ Bt,
                     float* __restrict__ C, int M, int N, int K, int kPerSplit) {
    __shared__ __align__(16) __fp16 As[BM][BKP];
    __shared__ __align__(16) __fp16 Bs[BN][BKP];

    const int bm = blockIdx.x * BM;
    const int bn = blockIdx.y * BN;
    const int k0 = blockIdx.z * kPerSplit;
    const int kEnd = k0 + kPerSplit;

    const int tid  = threadIdx.x;
    const int lane = tid & 63;
    const int wave = tid >> 6;          // 0..3
    const int wm   = (wave >> 1) * 64;  // 0 or 64
    const int wn   = (wave & 1) * 64;   // 0 or 64
    const int quad = lane >> 4;         // 0..3
    const int l16  = lane & 15;

    f32x4 acc[4][4];
#pragma unroll
    for (int ti = 0; ti < 4; ++ti)
#pragma unroll
        for (int tj = 0; tj < 4; ++tj)
            acc[ti][tj] = (f32x4){0.f, 0.f, 0.f, 0.f};

    for (int kc = k0; kc < kEnd; kc += BK) {
        // ---- stage A tile: 128 rows x 32 k = 1024 float4, 4 per thread ----
#pragma unroll
        for (int s = 0; s < 4; ++s) {
            int c   = tid + s * 256;
            int row = c >> 3;          // 0..127
            int kq  = c & 7;           // float4 index within the 32-k row
            const float4 v = *reinterpret_cast<const float4*>(
                &A[(size_t)(bm + row) * K + kc + kq * 4]);
            *reinterpret_cast<f16x2*>(&As[row][kq * 4 + 0]) = __builtin_amdgcn_cvt_pkrtz(v.x, v.y);
            *reinterpret_cast<f16x2*>(&As[row][kq * 4 + 2]) = __builtin_amdgcn_cvt_pkrtz(v.z, v.w);
        }
        // ---- stage B tile ----
#pragma unroll
        for (int s = 0; s < 4; ++s) {
            int c   = tid + s * 256;
            int row = c >> 3;
            int kq  = c & 7;
            const float4 v = *reinterpret_cast<const float4*>(
                &Bt[(size_t)(bn + row) * K + kc + kq * 4]);
            *reinterpret_cast<f16x2*>(&Bs[row][kq * 4 + 0]) = __builtin_amdgcn_cvt_pkrtz(v.x, v.y);
            *reinterpret_cast<f16x2*>(&Bs[row][kq * 4 + 2]) = __builtin_amdgcn_cvt_pkrtz(v.z, v.w);
        }
        __syncthreads();

        // ---- fragments + 16 MFMA ----
        f16x8 af[4], bf[4];
#pragma unroll
        for (int t = 0; t < 4; ++t) {
            af[t] = *reinterpret_cast<const f16x8*>(&As[wm + t * 16 + l16][quad * 8]);
            bf[t] = *reinterpret_cast<const f16x8*>(&Bs[wn + t * 16 + l16][quad * 8]);
        }
#pragma unroll
        for (int ti = 0; ti < 4; ++ti)
#pragma unroll
            for (int tj = 0; tj < 4; ++tj)
                acc[ti][tj] = __builtin_amdgcn_mfma_f32_16x16x32_f16(
                    af[ti], bf[tj], acc[ti][tj], 0, 0, 0);
        __syncthreads();
    }

    // ---- epilogue: atomic accumulate (split-K) ----
#pragma unroll
    for (int ti = 0; ti < 4; ++ti) {
#pragma unroll
        for (int tj = 0; tj < 4; ++tj) {
#pragma unroll
            for (int r = 0; r < 4; ++r) {
                int row = bm + wm + ti * 16 + quad * 4 + r;
                int col = bn + wn + tj * 16 + l16;
                atomicAdd(&C[(size_t)row * N + col], acc[ti][tj][r]);
            }
        }
    }
}

// ---------------------------------------------------------------------------
extern "C" void kernel_launch(void* const* d_in, const int* in_sizes, int n_in,
                              void* d_out, int out_size, void* d_ws, size_t ws_size,
                              hipStream_t stream) {
    const float* a  = (const float*)d_in[0];   // [8192][8192]
    const float* x  = (const float*)d_in[1];   // [8192][256][8] -> [m][k=i*8+r]
    const float* wb = (const float*)d_in[2];   // [4][256][256]
    const float* wr = (const float*)d_in[3];   // [8][4]
    float* out = (float*)d_out;                // [8192][256]

    float* W2T = (float*)d_ws;                                     // [256][2048], 2 MB
    float* yT  = (float*)((char*)d_ws + (size_t)OUTC * K2 * 4);    // [256][8192], 8 MB

    // zero atomic-accumulation targets (harness poisons them with 0xAA)
    (void)hipMemsetAsync(yT,  0, (size_t)OUTC * NN * sizeof(float), stream);
    (void)hipMemsetAsync(out, 0, (size_t)NN * OUTC * sizeof(float), stream);

    // 1) combined basis weights, transposed: W2T[o][k]
    build_w2t<<<dim3(K2), dim3(256), 0, stream>>>(wb, wr, W2T);

    // 2) yT[o][m] = sum_k W2T[o][k] * x[m][k]   (M=256, N=8192, K=2048, split 4)
    //    grid 2*64*4 = 512 blocks -> 25% occupancy cap
    gemm_f16_splitk<<<dim3(2, 64, 4), dim3(256), 0, stream>>>(
        W2T, x, yT, 256, NN, K2, 512);

    // 3) out[n][o] = sum_m a[n][m] * yT[o][m]   (M=8192, N=256, K=8192, split 8)
    //    grid 64*2*8 = 1024 blocks -> 50% occupancy cap
    gemm_f16_splitk<<<dim3(64, 2, 8), dim3(256), 0, stream>>>(
        a, yT, out, NN, OUTC, NN, 1024);
}

// Round 4
// 497.376 us; speedup vs baseline: 1.0922x; 1.0475x over previous
//
#include <hip/hip_runtime.h>
#include <hip/hip_bf16.h>
#include <stdint.h>

typedef __fp16 f16x2 __attribute__((ext_vector_type(2)));
typedef __fp16 f16x8 __attribute__((ext_vector_type(8)));
typedef float  f32x4 __attribute__((ext_vector_type(4)));

#define GLOBAL_AS __attribute__((address_space(1)))
#define LDS_AS    __attribute__((address_space(3)))

#define NN   8192
#define INC  256
#define OUTC 256
#define K2   2048                    // INC * RR
#define YTN  ((size_t)OUTC * NN)     // 2M elements

__device__ __forceinline__ void async_copy16(const void* g, void* l) {
    // 16B per lane; LDS dest = wave-uniform base + lane*16 (m97/m104 semantics)
    __builtin_amdgcn_global_load_lds((const GLOBAL_AS uint32_t*)g,
                                     (LDS_AS uint32_t*)l, 16, 0, 0);
}

// ---------------------------------------------------------------------------
// W2T16[o][k] = sum_b w_rel[r,b] * w_bases[b,i,o],  k = i*8+r, f16 output.
// One block per o; thread i covers k = i*8..i*8+7 (contiguous f16x8 store).
// ---------------------------------------------------------------------------
__global__ void build_w2t16(const float* __restrict__ wb, const float* __restrict__ wr,
                            __fp16* __restrict__ W2T16) {
    int o = blockIdx.x;      // 0..255
    int i = threadIdx.x;     // 0..255
    float s[8];
#pragma unroll
    for (int r = 0; r < 8; ++r) s[r] = 0.f;
#pragma unroll
    for (int b = 0; b < 4; ++b) {
        float w = wb[((size_t)((b << 8) + i)) * OUTC + o];
#pragma unroll
        for (int r = 0; r < 8; ++r) s[r] = fmaf(wr[r * 4 + b], w, s[r]);
    }
    f16x8 out;
    f16x2* p = (f16x2*)&out;
    p[0] = __builtin_amdgcn_cvt_pkrtz(s[0], s[1]);
    p[1] = __builtin_amdgcn_cvt_pkrtz(s[2], s[3]);
    p[2] = __builtin_amdgcn_cvt_pkrtz(s[4], s[5]);
    p[3] = __builtin_amdgcn_cvt_pkrtz(s[6], s[7]);
    *reinterpret_cast<f16x8*>(&W2T16[(size_t)o * K2 + i * 8]) = out;
}

// ---------------------------------------------------------------------------
// Mixed-precision split-K GEMM, m97 structure:
//   Cpart[z][M][N] = A[M][K] * Bt[N][K]^T  over k-slice z
// One operand may be fp32 (staged fp32 via global_load_lds, cvt at frag read),
// the other f16 (staged f16 via global_load_lds). Plain stores, no atomics.
// Tile 128x128xBK32, 256 thr = 4 waves (2x2), wave = 64x64 = 4x4 mfma 16x16x32.
// ---------------------------------------------------------------------------
constexpr int BM = 128, BN = 128, BK = 32;

template <bool AF32, bool BF32>
__global__ __launch_bounds__(256, 2)
void gemm_mixed(const void* __restrict__ Ap, const void* __restrict__ Bp,
                float* __restrict__ Cp, int M, int N, int K, int kPerSplit) {
    constexpr int ABYTES = BM * BK * (AF32 ? 4 : 2);
    constexpr int BBYTES = BN * BK * (BF32 ? 4 : 2);
    __shared__ __align__(16) char smem[ABYTES + BBYTES];
    char* As = smem;
    char* Bs = smem + ABYTES;

    const int bm = blockIdx.x * BM;
    const int bn = blockIdx.y * BN;
    const int k0 = blockIdx.z * kPerSplit;

    const int tid  = threadIdx.x;
    const int lane = tid & 63;
    const int wave = tid >> 6;          // 0..3
    const int wm   = (wave >> 1) * 64;
    const int wn   = (wave & 1) * 64;
    const int quad = lane >> 4;
    const int l16  = lane & 15;

    f32x4 acc[4][4];
#pragma unroll
    for (int ti = 0; ti < 4; ++ti)
#pragma unroll
        for (int tj = 0; tj < 4; ++tj)
            acc[ti][tj] = (f32x4){0.f, 0.f, 0.f, 0.f};

    for (int kc = k0; kc < k0 + kPerSplit; kc += BK) {
        // ---- stage A rows [wave*32, wave*32+32) ----
        if (AF32) {
            const float* Ag = (const float*)Ap;
#pragma unroll
            for (int i = 0; i < 4; ++i) {             // 8 rows per instr
                int r0 = wave * 32 + i * 8;
                const float* g = Ag + (size_t)(bm + r0 + (lane >> 3)) * K + kc + ((lane & 7) << 2);
                async_copy16(g, As + (size_t)r0 * BK * 4);
            }
        } else {
            const __fp16* Ag = (const __fp16*)Ap;
#pragma unroll
            for (int i = 0; i < 2; ++i) {             // 16 rows per instr
                int r0 = wave * 32 + i * 16;
                const __fp16* g = Ag + (size_t)(bm + r0 + (lane >> 2)) * K + kc + ((lane & 3) << 3);
                async_copy16(g, As + (size_t)r0 * BK * 2);
            }
        }
        // ---- stage B rows [wave*32, wave*32+32) ----
        if (BF32) {
            const float* Bg = (const float*)Bp;
#pragma unroll
            for (int i = 0; i < 4; ++i) {
                int r0 = wave * 32 + i * 8;
                const float* g = Bg + (size_t)(bn + r0 + (lane >> 3)) * K + kc + ((lane & 7) << 2);
                async_copy16(g, Bs + (size_t)r0 * BK * 4);
            }
        } else {
            const __fp16* Bg = (const __fp16*)Bp;
#pragma unroll
            for (int i = 0; i < 2; ++i) {
                int r0 = wave * 32 + i * 16;
                const __fp16* g = Bg + (size_t)(bn + r0 + (lane >> 2)) * K + kc + ((lane & 3) << 3);
                async_copy16(g, Bs + (size_t)r0 * BK * 2);
            }
        }
        __syncthreads();   // drains vmcnt -> all LDS writes visible

        // ---- fragments ----
        f16x8 af[4], bf[4];
#pragma unroll
        for (int t = 0; t < 4; ++t) {
            if (AF32) {
                const float* Ar = (const float*)As + (size_t)(wm + t * 16 + l16) * BK + quad * 8;
                f32x4 u0 = *(const f32x4*)Ar;
                f32x4 u1 = *(const f32x4*)(Ar + 4);
                f16x2* p = (f16x2*)&af[t];
                p[0] = __builtin_amdgcn_cvt_pkrtz(u0[0], u0[1]);
                p[1] = __builtin_amdgcn_cvt_pkrtz(u0[2], u0[3]);
                p[2] = __builtin_amdgcn_cvt_pkrtz(u1[0], u1[1]);
                p[3] = __builtin_amdgcn_cvt_pkrtz(u1[2], u1[3]);
            } else {
                af[t] = *(const f16x8*)((const __fp16*)As + (size_t)(wm + t * 16 + l16) * BK + quad * 8);
            }
            if (BF32) {
                const float* Br = (const float*)Bs + (size_t)(wn + t * 16 + l16) * BK + quad * 8;
                f32x4 u0 = *(const f32x4*)Br;
                f32x4 u1 = *(const f32x4*)(Br + 4);
                f16x2* p = (f16x2*)&bf[t];
                p[0] = __builtin_amdgcn_cvt_pkrtz(u0[0], u0[1]);
                p[1] = __builtin_amdgcn_cvt_pkrtz(u0[2], u0[3]);
                p[2] = __builtin_amdgcn_cvt_pkrtz(u1[0], u1[1]);
                p[3] = __builtin_amdgcn_cvt_pkrtz(u1[2], u1[3]);
            } else {
                bf[t] = *(const f16x8*)((const __fp16*)Bs + (size_t)(wn + t * 16 + l16) * BK + quad * 8);
            }
        }
#pragma unroll
        for (int ti = 0; ti < 4; ++ti)
#pragma unroll
            for (int tj = 0; tj < 4; ++tj)
                acc[ti][tj] = __builtin_amdgcn_mfma_f32_16x16x32_f16(
                    af[ti], bf[tj], acc[ti][tj], 0, 0, 0);
        __syncthreads();
    }

    // ---- epilogue: plain stores into this z-split's partial slice ----
    float* Cz = Cp + (size_t)blockIdx.z * M * N;
#pragma unroll
    for (int ti = 0; ti < 4; ++ti)
#pragma unroll
        for (int tj = 0; tj < 4; ++tj)
#pragma unroll
            for (int r = 0; r < 4; ++r) {
                int row = bm + wm + ti * 16 + quad * 4 + r;
                int col = bn + wn + tj * 16 + l16;
                Cz[(size_t)row * N + col] = acc[ti][tj][r];
            }
}

// ---------------------------------------------------------------------------
// yT16[i] = (f16) sum_{z<4} yT_p[z][i]   (i over 256*8192, 8 per thread)
// ---------------------------------------------------------------------------
__global__ void reduce_yT(const float* __restrict__ yTp, __fp16* __restrict__ yT16) {
    size_t base = ((size_t)blockIdx.x * 256 + threadIdx.x) * 8;
    f32x4 s0 = (f32x4){0.f, 0.f, 0.f, 0.f};
    f32x4 s1 = (f32x4){0.f, 0.f, 0.f, 0.f};
#pragma unroll
    for (int z = 0; z < 4; ++z) {
        const float* p = yTp + (size_t)z * YTN + base;
        s0 += *(const f32x4*)p;
        s1 += *(const f32x4*)(p + 4);
    }
    f16x8 out;
    f16x2* p = (f16x2*)&out;
    p[0] = __builtin_amdgcn_cvt_pkrtz(s0[0], s0[1]);
    p[1] = __builtin_amdgcn_cvt_pkrtz(s0[2], s0[3]);
    p[2] = __builtin_amdgcn_cvt_pkrtz(s1[0], s1[1]);
    p[3] = __builtin_amdgcn_cvt_pkrtz(s1[2], s1[3]);
    *reinterpret_cast<f16x8*>(&yT16[base]) = out;
}

// ---------------------------------------------------------------------------
// out[i] = sum_{z<8} out_p[z][i]   (i over 8192*256, 4 per thread)
// ---------------------------------------------------------------------------
__global__ void reduce_out(const float* __restrict__ op, float* __restrict__ out) {
    size_t base = ((size_t)blockIdx.x * 256 + threadIdx.x) * 4;
    f32x4 s = (f32x4){0.f, 0.f, 0.f, 0.f};
#pragma unroll
    for (int z = 0; z < 8; ++z)
        s += *(const f32x4*)(op + (size_t)z * YTN + base);
    *reinterpret_cast<f32x4*>(&out[base]) = s;
}

// ---------------------------------------------------------------------------
extern "C" void kernel_launch(void* const* d_in, const int* in_sizes, int n_in,
                              void* d_out, int out_size, void* d_ws, size_t ws_size,
                              hipStream_t stream) {
    const float* a  = (const float*)d_in[0];   // [8192][8192]
    const float* x  = (const float*)d_in[1];   // [8192][2048] (k = i*8+r contiguous)
    const float* wb = (const float*)d_in[2];   // [4][256][256]
    const float* wr = (const float*)d_in[3];   // [8][4]
    float* out = (float*)d_out;                // [8192][256]

    // ws layout (101 MB total):
    //   [0,   32MB)  yT_p   : 4 x [256][8192] fp32 partials
    //   [32,  36MB)  yT16   : [256][8192] f16
    //   [36, 100MB)  out_p  : 8 x [8192][256] fp32 partials
    //   [100,101MB)  W2T16  : [256][2048] f16
    char* w = (char*)d_ws;
    float*  yT_p  = (float*)(w);
    __fp16* yT16  = (__fp16*)(w + ((size_t)32 << 20));
    float*  out_p = (float*)(w + ((size_t)36 << 20));
    __fp16* W2T16 = (__fp16*)(w + ((size_t)100 << 20));

    // 1) basis-combined weights, f16, [o][k]
    build_w2t16<<<dim3(256), dim3(256), 0, stream>>>(wb, wr, W2T16);

    // 2) yT_p[z][o][m] = W2T16[o][:] . x[m][:]   M=256,N=8192,K=2048, split 4
    gemm_mixed<false, true><<<dim3(2, 64, 4), dim3(256), 0, stream>>>(
        W2T16, x, yT_p, 256, NN, K2, 512);

    // 3) yT16 = f16(sum_z yT_p)
    reduce_yT<<<dim3(1024), dim3(256), 0, stream>>>(yT_p, yT16);

    // 4) out_p[z][n][o] = a[n][:] . yT16[o][:]   M=8192,N=256,K=8192, split 8
    gemm_mixed<true, false><<<dim3(64, 2, 8), dim3(256), 0, stream>>>(
        a, yT16, out_p, NN, OUTC, NN, 1024);

    // 5) out = sum_z out_p
    reduce_out<<<dim3(2048), dim3(256), 0, stream>>>(out_p, out);
}